// Round 7
// baseline (358.297 us; speedup 1.0000x reference)
//
#include <hip/hip_runtime.h>
#include <hip/hip_bf16.h>

// ---------------------------------------------------------------------------
// HeteroGNN forward (round 7):
//   - GEMM rewrite: A (f32 X) global->register->bf16, never through LDS, so
//     the barrier drain only covers L2-hot B staging. B: BK=128 chunk in LDS
//     (64 KB single buffer, 2 blocks/CU) with XOR-swizzled layout
//     (conflict-free ds_read_b128 beats). 313 blocks x 4 waves x 16 rows.
//   - fixed-capacity adjacency, gather-based aggregation, fused posts
// ---------------------------------------------------------------------------

#define H 128
#define K_DIM 1280
#define LIG_IN 4
#define CAP_L 24    // max ligand degree (lambda=2.5; observed max ~13)
#define CAP_T 48    // max target degree (lambda=12.5; observed max ~34)

typedef __attribute__((ext_vector_type(8))) short bf16x8;
typedef __attribute__((ext_vector_type(4))) float f32x4;

#define AS1(p) ((const __attribute__((address_space(1))) void*)(p))
#define AS3(p) ((__attribute__((address_space(3))) void*)(p))

// ---- kernel 1: build both fixed-capacity adjacencies ----------------------
__global__ void fill_both(const int* __restrict__ src, const int* __restrict__ dst,
                          int* __restrict__ cur_l, int* __restrict__ cur_t,
                          int* __restrict__ adjd, int* __restrict__ adjs, int E)
{
    int e = blockIdx.x * blockDim.x + threadIdx.x;
    if (e >= E) return;
    int s = src[e], d = dst[e];
    int p = atomicAdd(&cur_l[s], 1);
    adjd[s * CAP_L + p] = d;
    int q = atomicAdd(&cur_t[d], 1);
    adjs[d * CAP_T + q] = s;
}

// ---- cast weights: Wt[n][k]; n<128 -> W_tl_l (y_tl), n>=128 -> W_lt_r -----
__global__ void cast_wt(const float* __restrict__ Wl, const float* __restrict__ Wr,
                        __hip_bfloat16* __restrict__ Wt, int n)
{
    int idx = blockIdx.x * blockDim.x + threadIdx.x;
    if (idx >= n) return;
    int nr = idx / K_DIM, k = idx - nr * K_DIM;
    float v = (nr < H) ? Wl[k * H + nr] : Wr[k * H + (nr - H)];
    Wt[idx] = __float2bfloat16(v);
}

// ---- GEMM: [M,1280] f32 @ [1280,256] bf16 -> y_tl | t_lin (f32) -----------
__device__ inline bf16x8 cvt8(float4 u, float4 v)
{
    union { __hip_bfloat16 h[8]; bf16x8 f; } r;
    r.h[0] = __float2bfloat16(u.x); r.h[1] = __float2bfloat16(u.y);
    r.h[2] = __float2bfloat16(u.z); r.h[3] = __float2bfloat16(u.w);
    r.h[4] = __float2bfloat16(v.x); r.h[5] = __float2bfloat16(v.y);
    r.h[6] = __float2bfloat16(v.z); r.h[7] = __float2bfloat16(v.w);
    return r.f;
}

#define NCHUNK 10          // K_DIM / 128
__global__ __launch_bounds__(256, 2)
void gemm_fused(const float* __restrict__ Xf,          // [M,1280] f32
                const unsigned short* __restrict__ Wt, // [256,1280] bf16 n-major
                float* __restrict__ y_tl, float* __restrict__ t_lin, int M)
{
    // B chunk: 256 n-rows x 128 k (bf16) = 64 KB.
    // Row = 256 B = 16 chunks of 16 B; chunk c stored at slot c ^ (n&15).
    __shared__ short Bs[256 * 128];

    const int t = threadIdx.x;
    const int w = t >> 6, lane = t & 63;
    const int m = lane & 15, q = lane >> 4;
    const int bm = blockIdx.x * 64;

    // A: wave w owns rows bm + w*16 .. +16; lane reads row (m), f32 seg q*8
    const int rowc = min(bm + w * 16 + m, M - 1);
    const float* gA = Xf + (size_t)rowc * K_DIM + q * 8;

    f32x4 acc[16];
#pragma unroll
    for (int j = 0; j < 16; ++j) acc[j] = (f32x4){0.f, 0.f, 0.f, 0.f};

    float4 a4[2][8];

    // ---- prologue: A chunk 0 (registers) + B chunk 0 (LDS) ----
#pragma unroll
    for (int s = 0; s < 4; ++s) {
        a4[0][2 * s]     = *(const float4*)(gA + s * 32);
        a4[0][2 * s + 1] = *(const float4*)(gA + s * 32 + 4);
    }
#pragma unroll
    for (int i = 0; i < 16; ++i) {
        int L = i * 256 + t;
        int n = L >> 4, cp = L & 15;
        int cc = cp ^ (n & 15);
        __builtin_amdgcn_global_load_lds(AS1(Wt + (size_t)n * K_DIM + cc * 8),
                                         AS3((char*)Bs + (i * 256 + w * 64) * 16), 16, 0, 0);
    }
    __syncthreads();

    for (int c = 0; c < NCHUNK; ++c) {
        const int cur = c & 1;
        // prefetch A chunk c+1 into the other register buffer (overlaps MFMA)
        if (c + 1 < NCHUNK) {
#pragma unroll
            for (int s = 0; s < 4; ++s) {
                a4[cur ^ 1][2 * s]     = *(const float4*)(gA + (c + 1) * 128 + s * 32);
                a4[cur ^ 1][2 * s + 1] = *(const float4*)(gA + (c + 1) * 128 + s * 32 + 4);
            }
        }
        // compute chunk c: 4 k-steps x 16 n-tiles
#pragma unroll
        for (int s = 0; s < 4; ++s) {
            bf16x8 aF = cvt8(a4[cur][2 * s], a4[cur][2 * s + 1]);
#pragma unroll
            for (int j = 0; j < 16; ++j) {
                bf16x8 bF = *(const bf16x8*)((const char*)Bs +
                              (j * 16 + m) * 256 + (((s * 4 + q) ^ m) * 16));
                acc[j] = __builtin_amdgcn_mfma_f32_16x16x32_bf16(aF, bF, acc[j], 0, 0, 0);
            }
        }
        __syncthreads();   // all waves done reading Bs chunk c
        if (c + 1 < NCHUNK) {
            const int kc = (c + 1) * 128;
#pragma unroll
            for (int i = 0; i < 16; ++i) {
                int L = i * 256 + t;
                int n = L >> 4, cp = L & 15;
                int cc = cp ^ (n & 15);
                __builtin_amdgcn_global_load_lds(AS1(Wt + (size_t)n * K_DIM + kc + cc * 8),
                                                 AS3((char*)Bs + (i * 256 + w * 64) * 16), 16, 0, 0);
            }
            __syncthreads();   // Bs chunk c+1 visible
        }
    }

    // ---- epilogue: n-col = j*16 + m; m-row = bm + w*16 + q*4 + r ----
#pragma unroll
    for (int j = 0; j < 16; ++j) {
        float* __restrict__ Y = (j < 8) ? y_tl : t_lin;
        int col = (j & 7) * 16 + m;
#pragma unroll
        for (int r = 0; r < 4; ++r) {
            int row = bm + w * 16 + q * 4 + r;
            if (row < M) Y[(size_t)row * H + col] = acc[j][r];
        }
    }
}

// ---- target post (wave per target): gather agg + linear + relu + dot ------
__global__ void target_post(const int* __restrict__ cur_t, const int* __restrict__ adjs,
                            const float* __restrict__ xl, const float* __restrict__ t_lin,
                            const float* __restrict__ W_lt_l, const float* __restrict__ b_lt_l,
                            const float* __restrict__ W_ep,
                            float* __restrict__ st, int NT)
{
    int wid = (blockIdx.x * blockDim.x + threadIdx.x) >> 6;
    int lane = threadIdx.x & 63;
    if (wid >= NT) return;
    int cnt = cur_t[wid];
    float a0 = 0.f, a1 = 0.f, a2 = 0.f, a3 = 0.f;
    for (int j = lane; j < cnt; j += 64) {
        int s = adjs[wid * CAP_T + j];
        float4 v = *(const float4*)(xl + (size_t)s * LIG_IN);
        a0 += v.x; a1 += v.y; a2 += v.z; a3 += v.w;
    }
#pragma unroll
    for (int off = 32; off > 0; off >>= 1) {
        a0 += __shfl_xor(a0, off);
        a1 += __shfl_xor(a1, off);
        a2 += __shfl_xor(a2, off);
        a3 += __shfl_xor(a3, off);
    }
    float inv = 1.0f / fmaxf((float)cnt, 1.0f);
    a0 *= inv; a1 *= inv; a2 *= inv; a3 *= inv;
    float acc = 0.f;
#pragma unroll
    for (int p = 0; p < 2; ++p) {
        int h = lane + p * 64;
        float v = a0 * W_lt_l[h] + a1 * W_lt_l[H + h] + a2 * W_lt_l[2 * H + h] +
                  a3 * W_lt_l[3 * H + h] + b_lt_l[h] + t_lin[(size_t)wid * H + h];
        v = fmaxf(v, 0.f);
        acc += v * W_ep[H + h];
    }
#pragma unroll
    for (int off = 32; off > 0; off >>= 1) acc += __shfl_down(acc, off);
    if (lane == 0) st[wid] = acc;
}

// ---- fused ligand gather + post (wave per ligand) -------------------------
__global__ void ligand_gather_post(const int* __restrict__ cur_l, const int* __restrict__ adjd,
                                   const float* __restrict__ y_tl,
                                   const float* __restrict__ xl,
                                   const float* __restrict__ W_tl_r, const float* __restrict__ b_tl_l,
                                   const float* __restrict__ W_ep,
                                   float* __restrict__ sl, int NL)
{
    int wid = (blockIdx.x * blockDim.x + threadIdx.x) >> 6;
    int lane = threadIdx.x & 63;
    if (wid >= NL) return;
    int cnt = cur_l[wid];
    float a0 = 0.f, a1 = 0.f;   // h = 2*lane, 2*lane+1
    for (int j = 0; j < cnt; ++j) {
        int d = adjd[wid * CAP_L + j];
        float2 f = ((const float2*)(y_tl + (size_t)d * H))[lane];  // one 512B row load
        a0 += f.x;
        a1 += f.y;
    }
    float inv = 1.0f / fmaxf((float)cnt, 1.0f);
    float4 x = *(const float4*)(xl + (size_t)wid * LIG_IN);
    float acc = 0.f;
    {
        int h = 2 * lane;
        float v = a0 * inv + b_tl_l[h] +
                  x.x * W_tl_r[h] + x.y * W_tl_r[H + h] +
                  x.z * W_tl_r[2 * H + h] + x.w * W_tl_r[3 * H + h];
        v = fmaxf(v, 0.f);
        acc += v * W_ep[h];
    }
    {
        int h = 2 * lane + 1;
        float v = a1 * inv + b_tl_l[h] +
                  x.x * W_tl_r[h] + x.y * W_tl_r[H + h] +
                  x.z * W_tl_r[2 * H + h] + x.w * W_tl_r[3 * H + h];
        v = fmaxf(v, 0.f);
        acc += v * W_ep[h];
    }
#pragma unroll
    for (int off = 32; off > 0; off >>= 1) acc += __shfl_down(acc, off);
    if (lane == 0) sl[wid] = acc;
}

// ---- final edge output ----------------------------------------------------
__global__ void edge_out(const int* __restrict__ src, const int* __restrict__ dst,
                         const float* __restrict__ sl, const float* __restrict__ st,
                         const float* __restrict__ b_ep, float* __restrict__ out, int E)
{
    int e = blockIdx.x * blockDim.x + threadIdx.x;
    if (e >= E) return;
    out[e] = sl[src[e]] + st[dst[e]] + b_ep[0];
}

// ---------------------------------------------------------------------------
extern "C" void kernel_launch(void* const* d_in, const int* in_sizes, int n_in,
                              void* d_out, int out_size, void* d_ws, size_t ws_size,
                              hipStream_t stream) {
    const float* x_ligand = (const float*)d_in[0];
    const float* x_target = (const float*)d_in[1];
    const int*   edge_src = (const int*)d_in[2];
    const int*   edge_dst = (const int*)d_in[3];
    const float* W_lt_l   = (const float*)d_in[4];
    const float* b_lt_l   = (const float*)d_in[5];
    const float* W_lt_r   = (const float*)d_in[6];
    const float* W_tl_l   = (const float*)d_in[7];
    const float* b_tl_l   = (const float*)d_in[8];
    const float* W_tl_r   = (const float*)d_in[9];
    const float* W_ep     = (const float*)d_in[10];
    const float* b_ep     = (const float*)d_in[11];
    float* out = (float*)d_out;

    const int NL = in_sizes[0] / LIG_IN;   // 100000
    const int NT = in_sizes[1] / K_DIM;    // 20000
    const int E  = in_sizes[2];            // 250000

    // ---- workspace layout (16B-aligned offsets) ----
    char* ws = (char*)d_ws;
    size_t off = 0;
    auto take = [&](size_t bytes) { size_t o = off; off += (bytes + 15) & ~(size_t)15; return o; };
    size_t off_Wt     = take((size_t)2 * H * K_DIM * 2); // 655 KB bf16
    size_t off_y_tl   = take((size_t)NT * H * 4);        // 10.24 MB
    size_t off_t_lin  = take((size_t)NT * H * 4);        // 10.24 MB
    size_t off_adjd   = take((size_t)NL * CAP_L * 4);    // 9.6 MB
    size_t off_adjs   = take((size_t)NT * CAP_T * 4);    // 3.84 MB
    size_t off_cur_l  = take((size_t)NL * 4);            // <- memset start
    size_t off_cur_t  = take((size_t)NT * 4);            // <- memset end
    size_t off_sl     = take((size_t)NL * 4);
    size_t off_st     = take((size_t)NT * 4);
    if (off > ws_size) {
        hipMemsetAsync(d_out, 0, (size_t)out_size * 4, stream);
        return;
    }

    __hip_bfloat16* Wt = (__hip_bfloat16*)(ws + off_Wt);
    float* y_tl  = (float*)(ws + off_y_tl);
    float* t_lin = (float*)(ws + off_t_lin);
    int*   adjd  = (int*)(ws + off_adjd);
    int*   adjs  = (int*)(ws + off_adjs);
    int*   cur_l = (int*)(ws + off_cur_l);
    int*   cur_t = (int*)(ws + off_cur_t);
    float* sl    = (float*)(ws + off_sl);
    float* st    = (float*)(ws + off_st);

    // zero the cursors (contiguous)
    hipMemsetAsync(cur_l, 0, off_sl - off_cur_l, stream);

    // 1. weight cast (GEMM needs it first)
    int nw = 2 * H * K_DIM;
    cast_wt<<<(nw + 255) / 256, 256, 0, stream>>>(W_tl_l, W_lt_r, Wt, nw);

    // 2. GEMM (reads x_target f32 directly; A never staged through LDS)
    gemm_fused<<<(NT + 63) / 64, 256, 0, stream>>>(x_target, (const unsigned short*)Wt,
                                                   y_tl, t_lin, NT);

    // 3. adjacency build (1 atomic per edge per side)
    fill_both<<<(E + 255) / 256, 256, 0, stream>>>(edge_src, edge_dst,
                                                   cur_l, cur_t, adjd, adjs, E);

    // 4. target post -> st (gathers x_ligand via adjs)
    target_post<<<(NT * 64 + 255) / 256, 256, 0, stream>>>(cur_t, adjs, x_ligand, t_lin,
                                                           W_lt_l, b_lt_l, W_ep, st, NT);
    // 5. ligand gather + post -> sl
    ligand_gather_post<<<(NL * 64 + 255) / 256, 256, 0, stream>>>(cur_l, adjd, y_tl, x_ligand,
                                                                  W_tl_r, b_tl_l, W_ep, sl, NL);
    // 6. edge output
    edge_out<<<(E + 255) / 256, 256, 0, stream>>>(edge_src, edge_dst, sl, st, b_ep, out, E);
}

// Round 8
// 301.598 us; speedup vs baseline: 1.1880x; 1.1880x over previous
//
#include <hip/hip_runtime.h>
#include <hip/hip_bf16.h>

// ---------------------------------------------------------------------------
// HeteroGNN forward (round 8 = round 7 with the scratch-spill fixed):
//   - GEMM: A (f32 X) global->register->bf16 (never through LDS); B: BK=128
//     chunk in LDS (64 KB) with XOR-swizzled conflict-free layout. The chunk
//     loop is FULLY UNROLLED so a4[cur] indexing is static -> stays in VGPRs
//     (round 7's runtime `cur` demoted a4 to scratch: 119 MB spill writes).
//   - fixed-capacity adjacency, gather-based aggregation, fused posts
// ---------------------------------------------------------------------------

#define H 128
#define K_DIM 1280
#define LIG_IN 4
#define CAP_L 24    // max ligand degree (lambda=2.5; observed max ~13)
#define CAP_T 48    // max target degree (lambda=12.5; observed max ~34)

typedef __attribute__((ext_vector_type(8))) short bf16x8;
typedef __attribute__((ext_vector_type(4))) float f32x4;

#define AS1(p) ((const __attribute__((address_space(1))) void*)(p))
#define AS3(p) ((__attribute__((address_space(3))) void*)(p))

// ---- kernel 1: build both fixed-capacity adjacencies ----------------------
__global__ void fill_both(const int* __restrict__ src, const int* __restrict__ dst,
                          int* __restrict__ cur_l, int* __restrict__ cur_t,
                          int* __restrict__ adjd, int* __restrict__ adjs, int E)
{
    int e = blockIdx.x * blockDim.x + threadIdx.x;
    if (e >= E) return;
    int s = src[e], d = dst[e];
    int p = atomicAdd(&cur_l[s], 1);
    adjd[s * CAP_L + p] = d;
    int q = atomicAdd(&cur_t[d], 1);
    adjs[d * CAP_T + q] = s;
}

// ---- cast weights: Wt[n][k]; n<128 -> W_tl_l (y_tl), n>=128 -> W_lt_r -----
__global__ void cast_wt(const float* __restrict__ Wl, const float* __restrict__ Wr,
                        __hip_bfloat16* __restrict__ Wt, int n)
{
    int idx = blockIdx.x * blockDim.x + threadIdx.x;
    if (idx >= n) return;
    int nr = idx / K_DIM, k = idx - nr * K_DIM;
    float v = (nr < H) ? Wl[k * H + nr] : Wr[k * H + (nr - H)];
    Wt[idx] = __float2bfloat16(v);
}

// ---- GEMM: [M,1280] f32 @ [1280,256] bf16 -> y_tl | t_lin (f32) -----------
__device__ inline bf16x8 cvt8(float4 u, float4 v)
{
    union { __hip_bfloat16 h[8]; bf16x8 f; } r;
    r.h[0] = __float2bfloat16(u.x); r.h[1] = __float2bfloat16(u.y);
    r.h[2] = __float2bfloat16(u.z); r.h[3] = __float2bfloat16(u.w);
    r.h[4] = __float2bfloat16(v.x); r.h[5] = __float2bfloat16(v.y);
    r.h[6] = __float2bfloat16(v.z); r.h[7] = __float2bfloat16(v.w);
    return r.f;
}

#define NCHUNK 10          // K_DIM / 128
__global__ __launch_bounds__(256, 2)
void gemm_fused(const float* __restrict__ Xf,          // [M,1280] f32
                const unsigned short* __restrict__ Wt, // [256,1280] bf16 n-major
                float* __restrict__ y_tl, float* __restrict__ t_lin, int M)
{
    // B chunk: 256 n-rows x 128 k (bf16) = 64 KB.
    // Row = 256 B = 16 chunks of 16 B; chunk c stored at slot c ^ (n&15).
    __shared__ short Bs[256 * 128];

    const int t = threadIdx.x;
    const int w = t >> 6, lane = t & 63;
    const int m = lane & 15, q = lane >> 4;
    const int bm = blockIdx.x * 64;

    // A: wave w owns rows bm + w*16 .. +16; lane reads row (m), f32 seg q*8
    const int rowc = min(bm + w * 16 + m, M - 1);
    const float* gA = Xf + (size_t)rowc * K_DIM + q * 8;

    f32x4 acc[16];
#pragma unroll
    for (int j = 0; j < 16; ++j) acc[j] = (f32x4){0.f, 0.f, 0.f, 0.f};

    float4 a4[2][8];

    // ---- prologue: A chunk 0 (registers) + B chunk 0 (LDS) ----
#pragma unroll
    for (int s = 0; s < 4; ++s) {
        a4[0][2 * s]     = *(const float4*)(gA + s * 32);
        a4[0][2 * s + 1] = *(const float4*)(gA + s * 32 + 4);
    }
#pragma unroll
    for (int i = 0; i < 16; ++i) {
        int L = i * 256 + t;
        int n = L >> 4, cp = L & 15;
        int cc = cp ^ (n & 15);
        __builtin_amdgcn_global_load_lds(AS1(Wt + (size_t)n * K_DIM + cc * 8),
                                         AS3((char*)Bs + (i * 256 + w * 64) * 16), 16, 0, 0);
    }
    __syncthreads();

#pragma unroll                              // <-- static `cur`: a4 stays in VGPRs
    for (int c = 0; c < NCHUNK; ++c) {
        const int cur = c & 1;
        // prefetch A chunk c+1 into the other register buffer (overlaps MFMA)
        if (c + 1 < NCHUNK) {
#pragma unroll
            for (int s = 0; s < 4; ++s) {
                a4[cur ^ 1][2 * s]     = *(const float4*)(gA + (c + 1) * 128 + s * 32);
                a4[cur ^ 1][2 * s + 1] = *(const float4*)(gA + (c + 1) * 128 + s * 32 + 4);
            }
        }
        // compute chunk c: 4 k-steps x 16 n-tiles
#pragma unroll
        for (int s = 0; s < 4; ++s) {
            bf16x8 aF = cvt8(a4[cur][2 * s], a4[cur][2 * s + 1]);
#pragma unroll
            for (int j = 0; j < 16; ++j) {
                bf16x8 bF = *(const bf16x8*)((const char*)Bs +
                              (j * 16 + m) * 256 + (((s * 4 + q) ^ m) * 16));
                acc[j] = __builtin_amdgcn_mfma_f32_16x16x32_bf16(aF, bF, acc[j], 0, 0, 0);
            }
        }
        __syncthreads();   // all waves done reading Bs chunk c
        if (c + 1 < NCHUNK) {
            const int kc = (c + 1) * 128;
#pragma unroll
            for (int i = 0; i < 16; ++i) {
                int L = i * 256 + t;
                int n = L >> 4, cp = L & 15;
                int cc = cp ^ (n & 15);
                __builtin_amdgcn_global_load_lds(AS1(Wt + (size_t)n * K_DIM + kc + cc * 8),
                                                 AS3((char*)Bs + (i * 256 + w * 64) * 16), 16, 0, 0);
            }
            __syncthreads();   // Bs chunk c+1 visible
        }
    }

    // ---- epilogue: n-col = j*16 + m; m-row = bm + w*16 + q*4 + r ----
#pragma unroll
    for (int j = 0; j < 16; ++j) {
        float* __restrict__ Y = (j < 8) ? y_tl : t_lin;
        int col = (j & 7) * 16 + m;
#pragma unroll
        for (int r = 0; r < 4; ++r) {
            int row = bm + w * 16 + q * 4 + r;
            if (row < M) Y[(size_t)row * H + col] = acc[j][r];
        }
    }
}

// ---- target post (wave per target): gather agg + linear + relu + dot ------
__global__ void target_post(const int* __restrict__ cur_t, const int* __restrict__ adjs,
                            const float* __restrict__ xl, const float* __restrict__ t_lin,
                            const float* __restrict__ W_lt_l, const float* __restrict__ b_lt_l,
                            const float* __restrict__ W_ep,
                            float* __restrict__ st, int NT)
{
    int wid = (blockIdx.x * blockDim.x + threadIdx.x) >> 6;
    int lane = threadIdx.x & 63;
    if (wid >= NT) return;
    int cnt = cur_t[wid];
    float a0 = 0.f, a1 = 0.f, a2 = 0.f, a3 = 0.f;
    for (int j = lane; j < cnt; j += 64) {
        int s = adjs[wid * CAP_T + j];
        float4 v = *(const float4*)(xl + (size_t)s * LIG_IN);
        a0 += v.x; a1 += v.y; a2 += v.z; a3 += v.w;
    }
#pragma unroll
    for (int off = 32; off > 0; off >>= 1) {
        a0 += __shfl_xor(a0, off);
        a1 += __shfl_xor(a1, off);
        a2 += __shfl_xor(a2, off);
        a3 += __shfl_xor(a3, off);
    }
    float inv = 1.0f / fmaxf((float)cnt, 1.0f);
    a0 *= inv; a1 *= inv; a2 *= inv; a3 *= inv;
    float acc = 0.f;
#pragma unroll
    for (int p = 0; p < 2; ++p) {
        int h = lane + p * 64;
        float v = a0 * W_lt_l[h] + a1 * W_lt_l[H + h] + a2 * W_lt_l[2 * H + h] +
                  a3 * W_lt_l[3 * H + h] + b_lt_l[h] + t_lin[(size_t)wid * H + h];
        v = fmaxf(v, 0.f);
        acc += v * W_ep[H + h];
    }
#pragma unroll
    for (int off = 32; off > 0; off >>= 1) acc += __shfl_down(acc, off);
    if (lane == 0) st[wid] = acc;
}

// ---- fused ligand gather + post (wave per ligand) -------------------------
__global__ void ligand_gather_post(const int* __restrict__ cur_l, const int* __restrict__ adjd,
                                   const float* __restrict__ y_tl,
                                   const float* __restrict__ xl,
                                   const float* __restrict__ W_tl_r, const float* __restrict__ b_tl_l,
                                   const float* __restrict__ W_ep,
                                   float* __restrict__ sl, int NL)
{
    int wid = (blockIdx.x * blockDim.x + threadIdx.x) >> 6;
    int lane = threadIdx.x & 63;
    if (wid >= NL) return;
    int cnt = cur_l[wid];
    float a0 = 0.f, a1 = 0.f;   // h = 2*lane, 2*lane+1
    for (int j = 0; j < cnt; ++j) {
        int d = adjd[wid * CAP_L + j];
        float2 f = ((const float2*)(y_tl + (size_t)d * H))[lane];  // one 512B row load
        a0 += f.x;
        a1 += f.y;
    }
    float inv = 1.0f / fmaxf((float)cnt, 1.0f);
    float4 x = *(const float4*)(xl + (size_t)wid * LIG_IN);
    float acc = 0.f;
    {
        int h = 2 * lane;
        float v = a0 * inv + b_tl_l[h] +
                  x.x * W_tl_r[h] + x.y * W_tl_r[H + h] +
                  x.z * W_tl_r[2 * H + h] + x.w * W_tl_r[3 * H + h];
        v = fmaxf(v, 0.f);
        acc += v * W_ep[h];
    }
    {
        int h = 2 * lane + 1;
        float v = a1 * inv + b_tl_l[h] +
                  x.x * W_tl_r[h] + x.y * W_tl_r[H + h] +
                  x.z * W_tl_r[2 * H + h] + x.w * W_tl_r[3 * H + h];
        v = fmaxf(v, 0.f);
        acc += v * W_ep[h];
    }
#pragma unroll
    for (int off = 32; off > 0; off >>= 1) acc += __shfl_down(acc, off);
    if (lane == 0) sl[wid] = acc;
}

// ---- final edge output ----------------------------------------------------
__global__ void edge_out(const int* __restrict__ src, const int* __restrict__ dst,
                         const float* __restrict__ sl, const float* __restrict__ st,
                         const float* __restrict__ b_ep, float* __restrict__ out, int E)
{
    int e = blockIdx.x * blockDim.x + threadIdx.x;
    if (e >= E) return;
    out[e] = sl[src[e]] + st[dst[e]] + b_ep[0];
}

// ---------------------------------------------------------------------------
extern "C" void kernel_launch(void* const* d_in, const int* in_sizes, int n_in,
                              void* d_out, int out_size, void* d_ws, size_t ws_size,
                              hipStream_t stream) {
    const float* x_ligand = (const float*)d_in[0];
    const float* x_target = (const float*)d_in[1];
    const int*   edge_src = (const int*)d_in[2];
    const int*   edge_dst = (const int*)d_in[3];
    const float* W_lt_l   = (const float*)d_in[4];
    const float* b_lt_l   = (const float*)d_in[5];
    const float* W_lt_r   = (const float*)d_in[6];
    const float* W_tl_l   = (const float*)d_in[7];
    const float* b_tl_l   = (const float*)d_in[8];
    const float* W_tl_r   = (const float*)d_in[9];
    const float* W_ep     = (const float*)d_in[10];
    const float* b_ep     = (const float*)d_in[11];
    float* out = (float*)d_out;

    const int NL = in_sizes[0] / LIG_IN;   // 100000
    const int NT = in_sizes[1] / K_DIM;    // 20000
    const int E  = in_sizes[2];            // 250000

    // ---- workspace layout (16B-aligned offsets) ----
    char* ws = (char*)d_ws;
    size_t off = 0;
    auto take = [&](size_t bytes) { size_t o = off; off += (bytes + 15) & ~(size_t)15; return o; };
    size_t off_Wt     = take((size_t)2 * H * K_DIM * 2); // 655 KB bf16
    size_t off_y_tl   = take((size_t)NT * H * 4);        // 10.24 MB
    size_t off_t_lin  = take((size_t)NT * H * 4);        // 10.24 MB
    size_t off_adjd   = take((size_t)NL * CAP_L * 4);    // 9.6 MB
    size_t off_adjs   = take((size_t)NT * CAP_T * 4);    // 3.84 MB
    size_t off_cur_l  = take((size_t)NL * 4);            // <- memset start
    size_t off_cur_t  = take((size_t)NT * 4);            // <- memset end
    size_t off_sl     = take((size_t)NL * 4);
    size_t off_st     = take((size_t)NT * 4);
    if (off > ws_size) {
        hipMemsetAsync(d_out, 0, (size_t)out_size * 4, stream);
        return;
    }

    __hip_bfloat16* Wt = (__hip_bfloat16*)(ws + off_Wt);
    float* y_tl  = (float*)(ws + off_y_tl);
    float* t_lin = (float*)(ws + off_t_lin);
    int*   adjd  = (int*)(ws + off_adjd);
    int*   adjs  = (int*)(ws + off_adjs);
    int*   cur_l = (int*)(ws + off_cur_l);
    int*   cur_t = (int*)(ws + off_cur_t);
    float* sl    = (float*)(ws + off_sl);
    float* st    = (float*)(ws + off_st);

    // zero the cursors (contiguous)
    hipMemsetAsync(cur_l, 0, off_sl - off_cur_l, stream);

    // 1. weight cast (GEMM needs it first)
    int nw = 2 * H * K_DIM;
    cast_wt<<<(nw + 255) / 256, 256, 0, stream>>>(W_tl_l, W_lt_r, Wt, nw);

    // 2. GEMM (reads x_target f32 directly; A never staged through LDS)
    gemm_fused<<<(NT + 63) / 64, 256, 0, stream>>>(x_target, (const unsigned short*)Wt,
                                                   y_tl, t_lin, NT);

    // 3. adjacency build (1 atomic per edge per side)
    fill_both<<<(E + 255) / 256, 256, 0, stream>>>(edge_src, edge_dst,
                                                   cur_l, cur_t, adjd, adjs, E);

    // 4. target post -> st (gathers x_ligand via adjs)
    target_post<<<(NT * 64 + 255) / 256, 256, 0, stream>>>(cur_t, adjs, x_ligand, t_lin,
                                                           W_lt_l, b_lt_l, W_ep, st, NT);
    // 5. ligand gather + post -> sl
    ligand_gather_post<<<(NL * 64 + 255) / 256, 256, 0, stream>>>(cur_l, adjd, y_tl, x_ligand,
                                                                  W_tl_r, b_tl_l, W_ep, sl, NL);
    // 6. edge output
    edge_out<<<(E + 255) / 256, 256, 0, stream>>>(edge_src, edge_dst, sl, st, b_ep, out, E);
}